// Round 10
// baseline (296.119 us; speedup 1.0000x reference)
//
#include <hip/hip_runtime.h>
#include <hip/hip_bf16.h>

typedef __bf16 bf16;
typedef bf16 bf16x8 __attribute__((ext_vector_type(8)));
typedef float f32x4 __attribute__((ext_vector_type(4)));

#define EPI_BIAS_RELU  0
#define EPI_BIAS_BF16  1
#define EPI_PLAIN_BF16 2
#define EPI_RESID      3
#define EPI_BIAS_F32   4

__device__ __forceinline__ void lds_load16(const bf16* g, bf16* l) {
  __builtin_amdgcn_global_load_lds((__attribute__((address_space(1))) void*)g,
                                   (__attribute__((address_space(3))) void*)l,
                                   16, 0, 0);
}

template<int N> __device__ __forceinline__ void vmw() {
  if constexpr (N == 0) asm volatile("s_waitcnt vmcnt(0)" ::: "memory");
  else if constexpr (N == 2) asm volatile("s_waitcnt vmcnt(2)" ::: "memory");
  else if constexpr (N == 4) asm volatile("s_waitcnt vmcnt(4)" ::: "memory");
  else if constexpr (N == 8) asm volatile("s_waitcnt vmcnt(8)" ::: "memory");
}
__device__ __forceinline__ void lgkm0() {
  asm volatile("s_waitcnt lgkmcnt(0)" ::: "memory");
}
__device__ __forceinline__ void barrier() { asm volatile("s_barrier" ::: "memory"); }

// Row-slab XCD mapping (r7-proven: FETCH near-ideal): XCD x owns a contiguous
// (z,by) slab; bx varies fastest. Bijective when (gy*gz)%8==0 (all our grids).
__device__ __forceinline__ void xcd_map(int& bx, int& by, int& z) {
  const int gx = gridDim.x, gy = gridDim.y;
  const int Y8 = (gy * gridDim.z) >> 3;
  const int L = (blockIdx.z * gy + blockIdx.y) * gx + blockIdx.x;
  const int xcd = L & 7, j = L >> 3;
  bx = j % gx;
  const int yy = xcd * Y8 + j / gx;
  by = yy % gy;
  z  = yy / gy;
}

// ============ 256x256 tile, 2-phase/K-tile (r8 structure, kk-outer) ============
template<int EPI>
__global__ __launch_bounds__(512, 2)
void gemm2x(const bf16* __restrict__ A, const bf16* __restrict__ B,
            void* __restrict__ Cv, const float* __restrict__ bias,
            int K, int lda, int ldb, int ldc,
            long long sAz, long long sBz, long long sCz)
{
  constexpr int BK = 64;
  constexpr int M_REP = 8, N_REP = 4, NH = 2;

  __shared__ __align__(16) bf16 lA[2][256 * BK];
  __shared__ __align__(16) bf16 lB[2][256 * BK];

  int bx, by, z;
  xcd_map(bx, by, z);

  const bf16* Ab = A + (size_t)z * sAz;
  const bf16* Bb = B + (size_t)z * sBz;
  const int row0 = by * 256, col0 = bx * 256;
  const int tid = threadIdx.x, w = tid >> 6, l = tid & 63;
  const int wr = w >> 2, wc = w & 3;

  const int srow = l >> 3, scb = (l & 7) ^ srow;
  const bf16* gA = Ab + (size_t)(row0 + w * 8 + srow) * lda + scb * 8;
  const bf16* gB = Bb + (size_t)(col0 + w * 8 + srow) * ldb + scb * 8;

  auto issueA = [&](int buf, int k0) {
#pragma unroll
    for (int i = 0; i < 4; i++)
      lds_load16(gA + (size_t)(i * 64) * lda + k0,
                 &lA[buf][(i * 64 + w * 8) * BK]);
  };
  auto issueB = [&](int buf, int k0) {
#pragma unroll
    for (int i = 0; i < 4; i++)
      lds_load16(gB + (size_t)(i * 64) * ldb + k0,
                 &lB[buf][(i * 64 + w * 8) * BK]);
  };

  const int fr = l & 15, fq = l >> 4, sw = fr & 7;
  bf16x8 aA[M_REP][2], bB0[NH][2], bB1[NH][2];
  f32x4 acc[M_REP][N_REP] = {};

  auto readAfull = [&](int buf) {
#pragma unroll
    for (int m = 0; m < M_REP; m++) {
      const int r = (m >> 2) * 128 + wr * 64 + (m & 3) * 16 + fr;
      const bf16* base = &lA[buf][r * BK];
#pragma unroll
      for (int kk = 0; kk < 2; kk++)
        aA[m][kk] = *(const bf16x8*)(base + ((kk * 4 + fq) ^ sw) * 8);
    }
  };
  auto readB = [&](bf16x8 (&dst)[NH][2], int buf, int h) {
#pragma unroll
    for (int nn = 0; nn < NH; nn++) {
      const bf16* base = &lB[buf][(h * 128 + wc * 32 + nn * 16 + fr) * BK];
#pragma unroll
      for (int kk = 0; kk < 2; kk++)
        dst[nn][kk] = *(const bf16x8*)(base + ((kk * 4 + fq) ^ sw) * 8);
    }
  };
  auto quad32 = [&](const bf16x8 (&b)[NH][2], int nBase) {
    __builtin_amdgcn_s_setprio(1);
#pragma unroll
    for (int kk = 0; kk < 2; kk++)
#pragma unroll
      for (int m = 0; m < M_REP; m++)
#pragma unroll
        for (int nh = 0; nh < NH; nh++)
          acc[m][nBase + nh] = __builtin_amdgcn_mfma_f32_16x16x32_bf16(
              aA[m][kk], b[nh][kk], acc[m][nBase + nh], 0, 0, 0);
    __builtin_amdgcn_s_setprio(0);
  };

  const int NT = K / BK;
  issueA(0, 0); issueB(0, 0); issueA(1, BK);
  vmw<4>();
  barrier();

  for (int t = 0; t < NT; t++) {
    const int cur = t & 1, nxt = cur ^ 1;
    const bool s1 = (t + 1 < NT), s2 = (t + 2 < NT);
    // p0
    readAfull(cur);
    readB(bB0, cur, 0);
    if (s1) issueB(nxt, (t + 1) * BK);
    barrier();
    quad32(bB0, 0);
    barrier();
    // p1
    readB(bB1, cur, 1);
    if (s2) { issueA(cur, (t + 2) * BK); vmw<4>(); }
    else vmw<0>();
    barrier();
    quad32(bB1, NH);
    barrier();
  }

  // epilogue: C/D layout col=lane&15, row=(lane>>4)*4+j  [verified m89]
#pragma unroll
  for (int m = 0; m < M_REP; m++) {
#pragma unroll
    for (int n = 0; n < N_REP; n++) {
      const int col = col0 + (n / NH) * 128 + wc * 32 + (n % NH) * 16 + fr;
#pragma unroll
      for (int j = 0; j < 4; j++) {
        const int rrow = row0 + (m >> 2) * 128 + wr * 64 + (m & 3) * 16 + fq * 4 + j;
        const float val = acc[m][n][j];
        if constexpr (EPI == EPI_PLAIN_BF16) {
          bf16* Cp = (bf16*)Cv + (size_t)z * sCz;
          Cp[(size_t)rrow * ldc + col] = (bf16)val;
        } else if constexpr (EPI == EPI_BIAS_BF16) {
          bf16* Cp = (bf16*)Cv;
          Cp[(size_t)rrow * ldc + col] = (bf16)(val + bias[col]);
        } else if constexpr (EPI == EPI_BIAS_RELU) {
          bf16* Cp = (bf16*)Cv;
          Cp[(size_t)rrow * ldc + col] = (bf16)fmaxf(val + bias[col], 0.f);
        }
      }
    }
  }
}

// ====== 256x256 tile, 2-phase, A = f32 source with FUSED cast (G1 only) ======
// A-path is reg-staged: 8x global_load_dwordx4 (f32) -> cvt -> 4x ds_write_b128
// to the SWIZZLED LDS address (write-side swizzle; global addr unswizzled).
// Placement identical to global_load_lds path: global block g -> LDS block
// g^(row&7), so fragment reads are unchanged.
// FIFO ledger (A-load = 8 vmem, B-issue = 4 vmem):
//  prologue: loadA(0)[8] issueB(0)[4] | vmw<4> forces A(0) | writeA(0)
//            loadA(1)[8] | vmw<8> forces B(0), leaves A(1) | lgkm0 | bar
//  p1(t),s1: vmw<4> forces A(t+1) [leaves B(t+1):4] | writeA->lA[nxt]
//            if s2 loadA(t+2)[8], vmw<8> forces B(t+1) else vmw<0>
//            lgkm0 (ds_write drain) | bar | MFMA | bar
// Overwrites: writeA(nxt) at p1(t) is 4 barriers after lA[nxt]'s last read
// (p0(t-1)); B(t+1) forced before end-of-p1 barrier, read at p0(t+1).
__global__ __launch_bounds__(512, 2)
void gemm2xa(const float* __restrict__ Af, const bf16* __restrict__ B,
             bf16* __restrict__ C, const float* __restrict__ bias,
             int K, int lda, int ldb, int ldc)
{
  constexpr int BK = 64;
  constexpr int M_REP = 8, N_REP = 4, NH = 2;

  __shared__ __align__(16) bf16 lA[2][256 * BK];
  __shared__ __align__(16) bf16 lB[2][256 * BK];

  int bx, by, z;
  xcd_map(bx, by, z);

  const int row0 = by * 256, col0 = bx * 256;
  const int tid = threadIdx.x, w = tid >> 6, l = tid & 63;
  const int wr = w >> 2, wc = w & 3;

  const int srow = l >> 3, cb0 = l & 7, scb = cb0 ^ srow;
  const float* gAf = Af + (size_t)(row0 + w * 8 + srow) * lda + cb0 * 8;
  const bf16*  gB  = B  + (size_t)(col0 + w * 8 + srow) * ldb + scb * 8;

  float4 aST[4][2];  // in-flight A stage (statically indexed - rule 20)

  auto loadA = [&](int k0) {
#pragma unroll
    for (int i = 0; i < 4; i++) {
      const float* p = gAf + (size_t)(i * 64) * lda + k0;
      aST[i][0] = *(const float4*)(p);
      aST[i][1] = *(const float4*)(p + 4);
    }
  };
  auto writeA = [&](int buf) {
#pragma unroll
    for (int i = 0; i < 4; i++) {
      bf16x8 o;
      o[0] = (bf16)aST[i][0].x; o[1] = (bf16)aST[i][0].y;
      o[2] = (bf16)aST[i][0].z; o[3] = (bf16)aST[i][0].w;
      o[4] = (bf16)aST[i][1].x; o[5] = (bf16)aST[i][1].y;
      o[6] = (bf16)aST[i][1].z; o[7] = (bf16)aST[i][1].w;
      *(bf16x8*)(&lA[buf][(i * 64 + w * 8 + srow) * BK + scb * 8]) = o;
    }
  };
  auto issueB = [&](int buf, int k0) {
#pragma unroll
    for (int i = 0; i < 4; i++)
      lds_load16(gB + (size_t)(i * 64) * ldb + k0,
                 &lB[buf][(i * 64 + w * 8) * BK]);
  };

  const int fr = l & 15, fq = l >> 4, sw = fr & 7;
  bf16x8 aA[M_REP][2], bB0[NH][2], bB1[NH][2];
  f32x4 acc[M_REP][N_REP] = {};

  auto readAfull = [&](int buf) {
#pragma unroll
    for (int m = 0; m < M_REP; m++) {
      const int r = (m >> 2) * 128 + wr * 64 + (m & 3) * 16 + fr;
      const bf16* base = &lA[buf][r * BK];
#pragma unroll
      for (int kk = 0; kk < 2; kk++)
        aA[m][kk] = *(const bf16x8*)(base + ((kk * 4 + fq) ^ sw) * 8);
    }
  };
  auto readB = [&](bf16x8 (&dst)[NH][2], int buf, int h) {
#pragma unroll
    for (int nn = 0; nn < NH; nn++) {
      const bf16* base = &lB[buf][(h * 128 + wc * 32 + nn * 16 + fr) * BK];
#pragma unroll
      for (int kk = 0; kk < 2; kk++)
        dst[nn][kk] = *(const bf16x8*)(base + ((kk * 4 + fq) ^ sw) * 8);
    }
  };
  auto quad32 = [&](const bf16x8 (&b)[NH][2], int nBase) {
    __builtin_amdgcn_s_setprio(1);
#pragma unroll
    for (int kk = 0; kk < 2; kk++)
#pragma unroll
      for (int m = 0; m < M_REP; m++)
#pragma unroll
        for (int nh = 0; nh < NH; nh++)
          acc[m][nBase + nh] = __builtin_amdgcn_mfma_f32_16x16x32_bf16(
              aA[m][kk], b[nh][kk], acc[m][nBase + nh], 0, 0, 0);
    __builtin_amdgcn_s_setprio(0);
  };

  const int NT = K / BK;
  // prologue per ledger above
  loadA(0);
  issueB(0, 0);
  vmw<4>();
  writeA(0);
  loadA(BK);
  vmw<8>();
  lgkm0();
  barrier();

  for (int t = 0; t < NT; t++) {
    const int cur = t & 1, nxt = cur ^ 1;
    const bool s1 = (t + 1 < NT), s2 = (t + 2 < NT);
    // p0
    readAfull(cur);
    readB(bB0, cur, 0);
    if (s1) issueB(nxt, (t + 1) * BK);
    barrier();
    quad32(bB0, 0);
    barrier();
    // p1
    readB(bB1, cur, 1);
    if (s1) {
      vmw<4>();                       // forces A(t+1), leaves B(t+1):4
      writeA(nxt);
      if (s2) { loadA((t + 2) * BK); vmw<8>(); }  // forces B(t+1)
      else vmw<0>();
      lgkm0();                        // ds_write drain before barrier
    } else {
      vmw<0>();
    }
    barrier();
    quad32(bB1, NH);
    barrier();
  }

  // epilogue (bias + relu, bf16 out)
#pragma unroll
  for (int m = 0; m < M_REP; m++) {
#pragma unroll
    for (int n = 0; n < N_REP; n++) {
      const int col = col0 + (n / NH) * 128 + wc * 32 + (n % NH) * 16 + fr;
#pragma unroll
      for (int j = 0; j < 4; j++) {
        const int rrow = row0 + (m >> 2) * 128 + wr * 64 + (m & 3) * 16 + fq * 4 + j;
        C[(size_t)rrow * ldc + col] = (bf16)fmaxf(acc[m][n][j] + bias[col], 0.f);
      }
    }
  }
}

// ============ 128x256 tile, 2-phase (r6-proven, kk-outer) ============
template<int EPI>
__global__ __launch_bounds__(512, 2)
void gemm2p(const bf16* __restrict__ A, const bf16* __restrict__ B,
            void* __restrict__ Cv, const float* __restrict__ bias,
            const bf16* __restrict__ resid,
            int K, int lda, int ldb, int ldc, int ldr,
            long long sAz, long long sBz, long long sCz, long long sRz)
{
  constexpr int BM = 128, BK = 64;
  constexpr int M_REP = 4, NH = 2;

  __shared__ __align__(16) bf16 lA[2][BM * BK];
  __shared__ __align__(16) bf16 lB[2][256 * BK];

  int bx, by, z;
  xcd_map(bx, by, z);

  const bf16* Ab = A + (size_t)z * sAz;
  const bf16* Bb = B + (size_t)z * sBz;
  const int row0 = by * BM, col0 = bx * 256;
  const int tid = threadIdx.x, w = tid >> 6, l = tid & 63;
  const int wr = w >> 2, wc = w & 3;

  const int srow = l >> 3, scb = (l & 7) ^ srow;
  const bf16* gA = Ab + (size_t)(row0 + w * 8 + srow) * lda + scb * 8;
  const bf16* gB = Bb + (size_t)(col0 + w * 8 + srow) * ldb + scb * 8;

  auto issueAfull = [&](int buf, int k0) {
#pragma unroll
    for (int i = 0; i < 2; i++)
      lds_load16(gA + (size_t)(i * 64) * lda + k0,
                 &lA[buf][(i * 64 + w * 8) * BK]);
  };
  auto issueBfull = [&](int buf, int k0) {
#pragma unroll
    for (int i = 0; i < 4; i++)
      lds_load16(gB + (size_t)(i * 64) * ldb + k0,
                 &lB[buf][(i * 64 + w * 8) * BK]);
  };

  const int fr = l & 15, fq = l >> 4, sw = fr & 7;
  bf16x8 aA[M_REP][2], bB0[NH][2], bB1[NH][2];
  f32x4 acc[M_REP][4] = {};

  auto readAfull = [&](int buf) {
#pragma unroll
    for (int m = 0; m < M_REP; m++) {
      const bf16* base = &lA[buf][(wr * 64 + m * 16 + fr) * BK];
#pragma unroll
      for (int kk = 0; kk < 2; kk++)
        aA[m][kk] = *(const bf16x8*)(base + ((kk * 4 + fq) ^ sw) * 8);
    }
  };
  auto readB = [&](bf16x8 (&dst)[NH][2], int buf, int h) {
#pragma unroll
    for (int nn = 0; nn < NH; nn++) {
      const bf16* base = &lB[buf][(h * 128 + wc * 32 + nn * 16 + fr) * BK];
#pragma unroll
      for (int kk = 0; kk < 2; kk++)
        dst[nn][kk] = *(const bf16x8*)(base + ((kk * 4 + fq) ^ sw) * 8);
    }
  };
  auto quad2 = [&](const bf16x8 (&b)[NH][2], int nBase) {
    __builtin_amdgcn_s_setprio(1);
#pragma unroll
    for (int kk = 0; kk < 2; kk++)
#pragma unroll
      for (int m = 0; m < M_REP; m++)
#pragma unroll
        for (int nh = 0; nh < NH; nh++)
          acc[m][nBase + nh] = __builtin_amdgcn_mfma_f32_16x16x32_bf16(
              aA[m][kk], b[nh][kk], acc[m][nBase + nh], 0, 0, 0);
    __builtin_amdgcn_s_setprio(0);
  };

  const int NT = K / BK;
  issueAfull(0, 0); issueBfull(0, 0); issueAfull(1, BK);
  vmw<2>();
  barrier();

  for (int t = 0; t < NT; t++) {
    const int cur = t & 1, nxt = cur ^ 1;
    const bool s1 = (t + 1 < NT), s2 = (t + 2 < NT);
    readAfull(cur);
    readB(bB0, cur, 0);
    if (s1) issueBfull(nxt, (t + 1) * BK);
    barrier();
    quad2(bB0, 0);
    barrier();
    readB(bB1, cur, 1);
    if (s2) { issueAfull(cur, (t + 2) * BK); vmw<2>(); }
    else vmw<0>();
    barrier();
    quad2(bB1, NH);
    barrier();
  }

#pragma unroll
  for (int m = 0; m < M_REP; m++) {
#pragma unroll
    for (int n = 0; n < 4; n++) {
      const int col = col0 + (n / NH) * 128 + wc * 32 + (n % NH) * 16 + fr;
#pragma unroll
      for (int j = 0; j < 4; j++) {
        const int rrow = row0 + wr * 64 + m * 16 + fq * 4 + j;
        const float val = acc[m][n][j];
        if constexpr (EPI == EPI_PLAIN_BF16) {
          bf16* Cp = (bf16*)Cv + (size_t)z * sCz;
          Cp[(size_t)rrow * ldc + col] = (bf16)val;
        } else if constexpr (EPI == EPI_BIAS_F32) {
          float* Cp = (float*)Cv;
          Cp[(size_t)rrow * ldc + col] = val + bias[col];
        } else if constexpr (EPI == EPI_BIAS_BF16) {
          bf16* Cp = (bf16*)Cv;
          Cp[(size_t)rrow * ldc + col] = (bf16)(val + bias[col]);
        } else if constexpr (EPI == EPI_BIAS_RELU) {
          bf16* Cp = (bf16*)Cv;
          Cp[(size_t)rrow * ldc + col] = (bf16)fmaxf(val + bias[col], 0.f);
        } else {  // EPI_RESID
          bf16* Cp = (bf16*)Cv + (size_t)z * sCz;
          const bf16* Rp = resid + (size_t)z * sRz;
          Cp[(size_t)rrow * ldc + col] = (bf16)(val + (float)Rp[(size_t)rrow * ldr + col]);
        }
      }
    }
  }
}

// ===== cast kernel: weights only (x is cast-fused into G1) + bias pack =====
__global__ __launch_bounds__(256)
void cast_w(const float* __restrict__ w1, const float* __restrict__ w2,
            const float* __restrict__ wq, const float* __restrict__ wk,
            const float* __restrict__ wv, const float* __restrict__ wo,
            const float* __restrict__ bq, const float* __restrict__ bk,
            bf16* __restrict__ w1b, bf16* __restrict__ w2b,
            bf16* __restrict__ wqkb, bf16* __restrict__ wvb,
            bf16* __restrict__ wob, float* __restrict__ bqk) {
  const int b = blockIdx.x;
  if (b >= 4096) {  // bias pack: 8 blocks, 2048 elems
    const int i = (b - 4096) * 256 + threadIdx.x;
    bqk[i] = (i < 1024) ? bq[i] * 0.03125f : bk[i - 1024];
    return;
  }
  const float* src; bf16* dst; int base; float scale = 1.f;
  if (b < 1024)      { src = w1; dst = w1b;  base = b; }
  else if (b < 2048) { src = w2; dst = w2b;  base = b - 1024; }
  else if (b < 2560) { src = wq; dst = wqkb;              base = b - 2048; scale = 0.03125f; }
  else if (b < 3072) { src = wk; dst = wqkb + (1 << 20);  base = b - 2560; }
  else if (b < 3584) { src = wv; dst = wvb;  base = b - 3072; }
  else               { src = wo; dst = wob;  base = b - 3584; }
  const int i = base * 256 + threadIdx.x;
  const float4* p = (const float4*)src;
  float4 a = p[2 * i], c = p[2 * i + 1];
  bf16x8 o8;
  o8[0] = (bf16)(a.x * scale); o8[1] = (bf16)(a.y * scale);
  o8[2] = (bf16)(a.z * scale); o8[3] = (bf16)(a.w * scale);
  o8[4] = (bf16)(c.x * scale); o8[5] = (bf16)(c.y * scale);
  o8[6] = (bf16)(c.z * scale); o8[7] = (bf16)(c.w * scale);
  ((bf16x8*)dst)[i] = o8;
}

// batched transpose: in (z, R x C, ld ldi) -> out (z, C x R)
__global__ __launch_bounds__(256)
void transpose_bf16(const bf16* __restrict__ in, bf16* __restrict__ out,
                    int R, int C, int ldi,
                    long long inZ, long long outZ) {
  __shared__ bf16 t[64][72];
  const bf16* ib = in + (size_t)blockIdx.z * inZ;
  bf16* ob = out + (size_t)blockIdx.z * outZ;
  const int r0 = blockIdx.y * 64, c0 = blockIdx.x * 64;
  const int tid = threadIdx.x;
#pragma unroll
  for (int p = 0; p < 2; p++) {
    int r = p * 32 + tid / 8, cc = (tid % 8) * 8;
    bf16x8 vv = *(const bf16x8*)(ib + (size_t)(r0 + r) * ldi + c0 + cc);
#pragma unroll
    for (int j = 0; j < 8; j++) t[r][cc + j] = vv[j];
  }
  __syncthreads();
#pragma unroll
  for (int p = 0; p < 2; p++) {
    int r = p * 32 + tid / 8, cc = (tid % 8) * 8;
    bf16x8 o;
#pragma unroll
    for (int j = 0; j < 8; j++) o[j] = t[cc + j][r];
    *(bf16x8*)(ob + (size_t)(c0 + r) * R + r0 + cc) = o;
  }
}

// row softmax in-place: S (nrows x 2048 bf16)
__global__ __launch_bounds__(256)
void softmax_rows(bf16* __restrict__ S) {
  const size_t row = blockIdx.x;
  const int t = threadIdx.x, wv_ = t >> 6, ln = t & 63;
  bf16x8 v8 = ((const bf16x8*)(S + row * 2048))[t];
  float v[8];
#pragma unroll
  for (int j = 0; j < 8; j++) v[j] = (float)v8[j];
  float m = v[0];
#pragma unroll
  for (int j = 1; j < 8; j++) m = fmaxf(m, v[j]);
  for (int o = 32; o; o >>= 1) m = fmaxf(m, __shfl_xor(m, o));
  __shared__ float redm[4], reds[4];
  if (ln == 0) redm[wv_] = m;
  __syncthreads();
  m = fmaxf(fmaxf(redm[0], redm[1]), fmaxf(redm[2], redm[3]));
  float e[8], s = 0.f;
#pragma unroll
  for (int j = 0; j < 8; j++) { e[j] = __expf(v[j] - m); s += e[j]; }
  for (int o = 32; o; o >>= 1) s += __shfl_xor(s, o);
  if (ln == 0) reds[wv_] = s;
  __syncthreads();
  s = reds[0] + reds[1] + reds[2] + reds[3];
  const float inv = 1.f / s;
  bf16x8 o8;
#pragma unroll
  for (int j = 0; j < 8; j++) o8[j] = (bf16)(e[j] * inv);
  ((bf16x8*)(S + row * 2048))[t] = o8;
}

extern "C" void kernel_launch(void* const* d_in, const int* in_sizes, int n_in,
                              void* d_out, int out_size, void* d_ws, size_t ws_size,
                              hipStream_t stream) {
  const float* x  = (const float*)d_in[0];
  const float* w1 = (const float*)d_in[1];
  const float* b1 = (const float*)d_in[2];
  const float* w2 = (const float*)d_in[3];
  const float* b2 = (const float*)d_in[4];
  const float* wq = (const float*)d_in[5];
  const float* bq = (const float*)d_in[6];
  const float* wk = (const float*)d_in[7];
  const float* bk = (const float*)d_in[8];
  const float* wv = (const float*)d_in[9];
  const float* bv = (const float*)d_in[10];
  const float* wo = (const float*)d_in[11];
  const float* bo = (const float*)d_in[12];
  float* out = (float*)d_out;

  char* ws = (char*)d_ws;
  const size_t MB = 1024ull * 1024ull;
  if (ws_size < 130 * MB) return;

  bf16* w1b  = (bf16*)(ws + 0 * MB);    // 4 MB
  bf16* w2b  = (bf16*)(ws + 4 * MB);    // 4 MB
  bf16* wqkb = (bf16*)(ws + 8 * MB);    // 4 MB: [2048][1024] = wq/32 ; wk
  bf16* wvb  = (bf16*)(ws + 12 * MB);   // 2 MB
  bf16* wob  = (bf16*)(ws + 14 * MB);   // 2 MB
  float* bqk = (float*)(ws + 16 * MB);  // 8 KB
  bf16* h1  = (bf16*)(ws + 33 * MB);    // 32 MB, dead after G2
  bf16* h   = (bf16*)(ws + 65 * MB);    // 16 MB, dead after Gqk/Gv
  bf16* qk  = (bf16*)(ws + 81 * MB);    // 32 MB [8192][2048] q-hat|k, dead after S
  bf16* vb  = (bf16*)(ws + 113 * MB);   // 16 MB, alive thru PV (residual)
  bf16* vT  = (bf16*)(ws + 17 * MB);    // 16 MB
  bf16* S   = (bf16*)(ws + 33 * MB);    // 32 MB over dead h1 (softmax in-place)
  bf16* ctx = (bf16*)(ws + 65 * MB);    // 16 MB over dead h

  // ---- weight casts (wq folds 1/32 scale) + bias pack, one dispatch ----
  cast_w<<<4104, 256, 0, stream>>>(w1, w2, wq, wk, wv, wo, bq, bk,
                                   w1b, w2b, wqkb, wvb, wob, bqk);

  // ---- 1: h1 = relu(x @ w1^T + b1), x cast FUSED   M=8192 N=2048 K=1024
  gemm2xa<<<dim3(8, 32, 1), 512, 0, stream>>>(
      x, w1b, h1, b1, 1024, 1024, 1024, 2048);
  // ---- 2: h = relu(h1 @ w2^T + b2)   M=8192 N=1024 K=2048  [128x256]
  gemm2p<EPI_BIAS_RELU><<<dim3(4, 64, 1), 512, 0, stream>>>(
      h1, w2b, h, b2, nullptr, 2048, 2048, 2048, 1024, 0, 0, 0, 0, 0);
  // ---- 3: [q/32 | k] = h @ wqkb^T + bqk   M=8192 N=2048 K=1024  [256x256]
  gemm2x<EPI_BIAS_BF16><<<dim3(8, 32, 1), 512, 0, stream>>>(
      h, wqkb, qk, bqk, 1024, 1024, 1024, 2048, 0, 0, 0);
  // ---- 4: v = h @ wv^T + bv   M=8192 N=1024 K=1024  [128x256]
  gemm2p<EPI_BIAS_BF16><<<dim3(4, 64, 1), 512, 0, stream>>>(
      h, wvb, vb, bv, nullptr, 1024, 1024, 1024, 1024, 0, 0, 0, 0, 0);
  // ---- v^T per batch (2048x1024 -> 1024x2048)
  transpose_bf16<<<dim3(16, 32, 4), 256, 0, stream>>>(
      vb, vT, 2048, 1024, 1024, 2048LL * 1024, 1024LL * 2048);
  // ---- 5: S = qhat @ k^T (scale pre-folded), batched z=4  [256x256]
  gemm2x<EPI_PLAIN_BF16><<<dim3(8, 8, 4), 512, 0, stream>>>(
      qk, qk + 1024, S, nullptr, 1024, 2048, 2048, 2048,
      2048LL * 2048, 2048LL * 2048, 2048LL * 2048);
  // ---- 6: P = softmax(S) in-place
  softmax_rows<<<8192, 256, 0, stream>>>(S);
  // ---- 7: ctx = P @ vT^T + v, batched   M=2048 N=1024 K=2048  [128x256]
  gemm2p<EPI_RESID><<<dim3(4, 16, 4), 512, 0, stream>>>(
      S, vT, ctx, nullptr, vb, 2048, 2048, 2048, 1024, 1024,
      2048LL * 2048, 1024LL * 2048, 2048LL * 1024, 2048LL * 1024);
  // ---- 8: out = ctx @ wo^T + bo (fp32)   M=8192 N=1024 K=1024  [128x256]
  gemm2p<EPI_BIAS_F32><<<dim3(4, 64, 1), 512, 0, stream>>>(
      ctx, wob, out, bo, nullptr, 1024, 1024, 1024, 1024, 0, 0, 0, 0, 0);
}

// Round 11
// 266.072 us; speedup vs baseline: 1.1129x; 1.1129x over previous
//
#include <hip/hip_runtime.h>
#include <hip/hip_bf16.h>

typedef __bf16 bf16;
typedef bf16 bf16x8 __attribute__((ext_vector_type(8)));
typedef float f32x4 __attribute__((ext_vector_type(4)));

#define EPI_BIAS_RELU  0
#define EPI_BIAS_BF16  1
#define EPI_PLAIN_BF16 2
#define EPI_RESID      3
#define EPI_BIAS_F32   4

__device__ __forceinline__ void lds_load16(const bf16* g, bf16* l) {
  __builtin_amdgcn_global_load_lds((__attribute__((address_space(1))) void*)g,
                                   (__attribute__((address_space(3))) void*)l,
                                   16, 0, 0);
}

template<int N> __device__ __forceinline__ void vmw() {
  if constexpr (N == 0) asm volatile("s_waitcnt vmcnt(0)" ::: "memory");
  else if constexpr (N == 4) asm volatile("s_waitcnt vmcnt(4)" ::: "memory");
}
__device__ __forceinline__ void barrier() { asm volatile("s_barrier" ::: "memory"); }

// Row-slab XCD mapping (r7-proven: FETCH near-ideal): XCD x owns a contiguous
// (z,by) slab; bx varies fastest. Bijective when (gy*gz)%8==0 (all our grids).
__device__ __forceinline__ void xcd_map(int& bx, int& by, int& z) {
  const int gx = gridDim.x, gy = gridDim.y;
  const int Y8 = (gy * gridDim.z) >> 3;
  const int L = (blockIdx.z * gy + blockIdx.y) * gx + blockIdx.x;
  const int xcd = L & 7, j = L >> 3;
  bx = j % gx;
  const int yy = xcd * Y8 + j / gx;
  by = yy % gy;
  z  = yy / gy;
}

// ========= 128x128 tile, BK=64, 4 waves, 64KB LDS -> 2 blocks/CU =========
// The r6/r8-proven 2-phase ledger at HALF the LDS so two blocks co-reside
// per CU (m114 implicit cross-block overlap — the m97 mechanism).
// p0: read A-full(t)[8] + B0(t)[4] | stage B(t+1)[4] | bar | 16 MFMA | bar
// p1: read B1(t)[4] | stage A(t+2)[4] + vmcnt(4) | bar | 16 MFMA | bar
// FIFO at p1(t) wait: A(t+1):4 [p1(t-1)], B(t+1):4 [p0(t)], A(t+2):4 [now]
// = 12 outstanding; vmcnt(4) forces A(t+1)+B(t+1), leaves A(t+2). Overwrites:
// B(t+1)->lB[nxt] issued 2 barriers after lB[nxt]'s last read (p1(t-1));
// A(t+2)->lA[cur] issued 1 barrier after lA[cur]'s last read (p0(t)).
// Tail: t=NT-2 drains vmcnt(0). MFMA kk-outer (no dependent back-to-back).
template<int EPI>
__global__ __launch_bounds__(256, 2)
void gemm2s(const bf16* __restrict__ A, const bf16* __restrict__ B,
            void* __restrict__ Cv, const float* __restrict__ bias,
            const bf16* __restrict__ resid,
            int K, int lda, int ldb, int ldc, int ldr,
            long long sAz, long long sBz, long long sCz, long long sRz)
{
  constexpr int BK = 64;
  constexpr int M_REP = 4, NH = 2;

  __shared__ __align__(16) bf16 lA[2][128 * BK];
  __shared__ __align__(16) bf16 lB[2][128 * BK];

  int bx, by, z;
  xcd_map(bx, by, z);

  const bf16* Ab = A + (size_t)z * sAz;
  const bf16* Bb = B + (size_t)z * sBz;
  const int row0 = by * 128, col0 = bx * 128;
  const int tid = threadIdx.x, w = tid >> 6, l = tid & 63;
  const int wr = w >> 1, wc = w & 1;

  // staging: lane l -> row l>>3, 16B col-block (l&7)^(l>>3) pre-swizzled on
  // the GLOBAL side; LDS dest stays linear (rule 21 both-sides).
  const int srow = l >> 3, scb = (l & 7) ^ srow;
  const bf16* gA = Ab + (size_t)(row0 + w * 8 + srow) * lda + scb * 8;
  const bf16* gB = Bb + (size_t)(col0 + w * 8 + srow) * ldb + scb * 8;

  auto issueA = [&](int buf, int k0) {  // 4 loads/wave: 128x64 tile
#pragma unroll
    for (int i = 0; i < 4; i++)
      lds_load16(gA + (size_t)(i * 32) * lda + k0,
                 &lA[buf][(i * 32 + w * 8) * BK]);
  };
  auto issueB = [&](int buf, int k0) {
#pragma unroll
    for (int i = 0; i < 4; i++)
      lds_load16(gB + (size_t)(i * 32) * ldb + k0,
                 &lB[buf][(i * 32 + w * 8) * BK]);
  };

  const int fr = l & 15, fq = l >> 4, sw = fr & 7;
  bf16x8 aA[M_REP][2], bB0[NH][2], bB1[NH][2];
  f32x4 acc[M_REP][4] = {};

  auto readAfull = [&](int buf) {
#pragma unroll
    for (int m = 0; m < M_REP; m++) {
      const bf16* base = &lA[buf][(wr * 64 + m * 16 + fr) * BK];
#pragma unroll
      for (int kk = 0; kk < 2; kk++)
        aA[m][kk] = *(const bf16x8*)(base + ((kk * 4 + fq) ^ sw) * 8);
    }
  };
  auto readB = [&](bf16x8 (&dst)[NH][2], int buf, int h) {
#pragma unroll
    for (int nn = 0; nn < NH; nn++) {
      const bf16* base = &lB[buf][(wc * 64 + h * 32 + nn * 16 + fr) * BK];
#pragma unroll
      for (int kk = 0; kk < 2; kk++)
        dst[nn][kk] = *(const bf16x8*)(base + ((kk * 4 + fq) ^ sw) * 8);
    }
  };
  auto quad16 = [&](const bf16x8 (&b)[NH][2], int nBase) {
    __builtin_amdgcn_s_setprio(1);
#pragma unroll
    for (int kk = 0; kk < 2; kk++)
#pragma unroll
      for (int m = 0; m < M_REP; m++)
#pragma unroll
        for (int nh = 0; nh < NH; nh++)
          acc[m][nBase + nh] = __builtin_amdgcn_mfma_f32_16x16x32_bf16(
              aA[m][kk], b[nh][kk], acc[m][nBase + nh], 0, 0, 0);
    __builtin_amdgcn_s_setprio(0);
  };

  const int NT = K / BK;
  issueA(0, 0); issueB(0, 0); issueA(1, BK);
  vmw<4>();
  barrier();

  for (int t = 0; t < NT; t++) {
    const int cur = t & 1, nxt = cur ^ 1;
    const bool s1 = (t + 1 < NT), s2 = (t + 2 < NT);
    // p0
    readAfull(cur);
    readB(bB0, cur, 0);
    if (s1) issueB(nxt, (t + 1) * BK);
    barrier();
    quad16(bB0, 0);
    barrier();
    // p1
    readB(bB1, cur, 1);
    if (s2) { issueA(cur, (t + 2) * BK); vmw<4>(); }
    else vmw<0>();
    barrier();
    quad16(bB1, NH);
    barrier();
  }

  // epilogue: C/D layout col=lane&15, row=(lane>>4)*4+j  [verified m89]
#pragma unroll
  for (int m = 0; m < M_REP; m++) {
#pragma unroll
    for (int n = 0; n < 4; n++) {
      const int col = col0 + wc * 64 + n * 16 + fr;
#pragma unroll
      for (int j = 0; j < 4; j++) {
        const int rrow = row0 + wr * 64 + m * 16 + fq * 4 + j;
        const float val = acc[m][n][j];
        if constexpr (EPI == EPI_PLAIN_BF16) {
          bf16* Cp = (bf16*)Cv + (size_t)z * sCz;
          Cp[(size_t)rrow * ldc + col] = (bf16)val;
        } else if constexpr (EPI == EPI_BIAS_F32) {
          float* Cp = (float*)Cv;
          Cp[(size_t)rrow * ldc + col] = val + bias[col];
        } else if constexpr (EPI == EPI_BIAS_BF16) {
          bf16* Cp = (bf16*)Cv;
          Cp[(size_t)rrow * ldc + col] = (bf16)(val + bias[col]);
        } else if constexpr (EPI == EPI_BIAS_RELU) {
          bf16* Cp = (bf16*)Cv;
          Cp[(size_t)rrow * ldc + col] = (bf16)fmaxf(val + bias[col], 0.f);
        } else {  // EPI_RESID
          bf16* Cp = (bf16*)Cv + (size_t)z * sCz;
          const bf16* Rp = resid + (size_t)z * sRz;
          Cp[(size_t)rrow * ldc + col] = (bf16)(val + (float)Rp[(size_t)rrow * ldr + col]);
        }
      }
    }
  }
}

// ===== single cast kernel: x + all weights (block-range dispatch) =====
__global__ __launch_bounds__(256)
void cast_all(const float* __restrict__ x,  const float* __restrict__ w1,
              const float* __restrict__ w2, const float* __restrict__ wq,
              const float* __restrict__ wk, const float* __restrict__ wv,
              const float* __restrict__ wo,
              bf16* __restrict__ xb, bf16* __restrict__ w1b,
              bf16* __restrict__ w2b, bf16* __restrict__ wqkb,
              bf16* __restrict__ wvb, bf16* __restrict__ wob) {
  const int b = blockIdx.x;
  const float* src; bf16* dst; int base; float scale = 1.f;
  if (b < 4096)      { src = x;  dst = xb;   base = b; }
  else if (b < 5120) { src = w1; dst = w1b;  base = b - 4096; }
  else if (b < 6144) { src = w2; dst = w2b;  base = b - 5120; }
  else if (b < 6656) { src = wq; dst = wqkb;              base = b - 6144; scale = 0.03125f; }
  else if (b < 7168) { src = wk; dst = wqkb + (1 << 20);  base = b - 6656; }
  else if (b < 7680) { src = wv; dst = wvb;  base = b - 7168; }
  else               { src = wo; dst = wob;  base = b - 7680; }
  const int i = base * 256 + threadIdx.x;
  const float4* p = (const float4*)src;
  float4 a = p[2 * i], c = p[2 * i + 1];
  bf16x8 o8;
  o8[0] = (bf16)(a.x * scale); o8[1] = (bf16)(a.y * scale);
  o8[2] = (bf16)(a.z * scale); o8[3] = (bf16)(a.w * scale);
  o8[4] = (bf16)(c.x * scale); o8[5] = (bf16)(c.y * scale);
  o8[6] = (bf16)(c.z * scale); o8[7] = (bf16)(c.w * scale);
  ((bf16x8*)dst)[i] = o8;
}

__global__ __launch_bounds__(256)
void pack_bias_qk(const float* __restrict__ bq, const float* __restrict__ bk,
                  float* __restrict__ o) {
  int i = blockIdx.x * 256 + threadIdx.x;  // 2048
  o[i] = (i < 1024) ? bq[i] * 0.03125f : bk[i - 1024];
}

// batched transpose: in (z, R x C, ld ldi) -> out (z, C x R)
__global__ __launch_bounds__(256)
void transpose_bf16(const bf16* __restrict__ in, bf16* __restrict__ out,
                    int R, int C, int ldi,
                    long long inZ, long long outZ) {
  __shared__ bf16 t[64][72];
  const bf16* ib = in + (size_t)blockIdx.z * inZ;
  bf16* ob = out + (size_t)blockIdx.z * outZ;
  const int r0 = blockIdx.y * 64, c0 = blockIdx.x * 64;
  const int tid = threadIdx.x;
#pragma unroll
  for (int p = 0; p < 2; p++) {
    int r = p * 32 + tid / 8, cc = (tid % 8) * 8;
    bf16x8 vv = *(const bf16x8*)(ib + (size_t)(r0 + r) * ldi + c0 + cc);
#pragma unroll
    for (int j = 0; j < 8; j++) t[r][cc + j] = vv[j];
  }
  __syncthreads();
#pragma unroll
  for (int p = 0; p < 2; p++) {
    int r = p * 32 + tid / 8, cc = (tid % 8) * 8;
    bf16x8 o;
#pragma unroll
    for (int j = 0; j < 8; j++) o[j] = t[cc + j][r];
    *(bf16x8*)(ob + (size_t)(c0 + r) * R + r0 + cc) = o;
  }
}

// row softmax in-place: S (nrows x 2048 bf16)
__global__ __launch_bounds__(256)
void softmax_rows(bf16* __restrict__ S) {
  const size_t row = blockIdx.x;
  const int t = threadIdx.x, wv_ = t >> 6, ln = t & 63;
  bf16x8 v8 = ((const bf16x8*)(S + row * 2048))[t];
  float v[8];
#pragma unroll
  for (int j = 0; j < 8; j++) v[j] = (float)v8[j];
  float m = v[0];
#pragma unroll
  for (int j = 1; j < 8; j++) m = fmaxf(m, v[j]);
  for (int o = 32; o; o >>= 1) m = fmaxf(m, __shfl_xor(m, o));
  __shared__ float redm[4], reds[4];
  if (ln == 0) redm[wv_] = m;
  __syncthreads();
  m = fmaxf(fmaxf(redm[0], redm[1]), fmaxf(redm[2], redm[3]));
  float e[8], s = 0.f;
#pragma unroll
  for (int j = 0; j < 8; j++) { e[j] = __expf(v[j] - m); s += e[j]; }
  for (int o = 32; o; o >>= 1) s += __shfl_xor(s, o);
  if (ln == 0) reds[wv_] = s;
  __syncthreads();
  s = reds[0] + reds[1] + reds[2] + reds[3];
  const float inv = 1.f / s;
  bf16x8 o8;
#pragma unroll
  for (int j = 0; j < 8; j++) o8[j] = (bf16)(e[j] * inv);
  ((bf16x8*)(S + row * 2048))[t] = o8;
}

extern "C" void kernel_launch(void* const* d_in, const int* in_sizes, int n_in,
                              void* d_out, int out_size, void* d_ws, size_t ws_size,
                              hipStream_t stream) {
  const float* x  = (const float*)d_in[0];
  const float* w1 = (const float*)d_in[1];
  const float* b1 = (const float*)d_in[2];
  const float* w2 = (const float*)d_in[3];
  const float* b2 = (const float*)d_in[4];
  const float* wq = (const float*)d_in[5];
  const float* bq = (const float*)d_in[6];
  const float* wk = (const float*)d_in[7];
  const float* bk = (const float*)d_in[8];
  const float* wv = (const float*)d_in[9];
  const float* bv = (const float*)d_in[10];
  const float* wo = (const float*)d_in[11];
  const float* bo = (const float*)d_in[12];
  float* out = (float*)d_out;

  char* ws = (char*)d_ws;
  const size_t MB = 1024ull * 1024ull;
  if (ws_size < 130 * MB) return;

  bf16* w1b  = (bf16*)(ws + 0 * MB);    // 4 MB
  bf16* w2b  = (bf16*)(ws + 4 * MB);    // 4 MB
  bf16* wqkb = (bf16*)(ws + 8 * MB);    // 4 MB: [2048][1024] = wq/32 ; wk
  bf16* wvb  = (bf16*)(ws + 12 * MB);   // 2 MB
  bf16* wob  = (bf16*)(ws + 14 * MB);   // 2 MB
  float* bqk = (float*)(ws + 16 * MB);  // 8 KB
  bf16* xb  = (bf16*)(ws + 17 * MB);    // 16 MB, dead after G1
  bf16* h1  = (bf16*)(ws + 33 * MB);    // 32 MB, dead after G2
  bf16* h   = (bf16*)(ws + 65 * MB);    // 16 MB, dead after Gqk/Gv
  bf16* qk  = (bf16*)(ws + 81 * MB);    // 32 MB [8192][2048] q-hat|k, dead after S
  bf16* vb  = (bf16*)(ws + 113 * MB);   // 16 MB, alive thru PV (residual)
  bf16* vT  = (bf16*)(ws + 17 * MB);    // 16 MB over dead xb
  bf16* S   = (bf16*)(ws + 33 * MB);    // 32 MB over dead h1 (softmax in-place)
  bf16* ctx = (bf16*)(ws + 65 * MB);    // 16 MB over dead h

  // ---- casts (wq folds 1/32 scale) + qk bias pack ----
  cast_all<<<8192, 256, 0, stream>>>(x, w1, w2, wq, wk, wv, wo,
                                     xb, w1b, w2b, wqkb, wvb, wob);
  pack_bias_qk<<<8, 256, 0, stream>>>(bq, bk, bqk);

  // ---- 1: h1 = relu(x @ w1^T + b1)   M=8192 N=2048 K=1024  [1024wg]
  gemm2s<EPI_BIAS_RELU><<<dim3(16, 64, 1), 256, 0, stream>>>(
      xb, w1b, h1, b1, nullptr, 1024, 1024, 1024, 2048, 0, 0, 0, 0, 0);
  // ---- 2: h = relu(h1 @ w2^T + b2)   M=8192 N=1024 K=2048  [512wg]
  gemm2s<EPI_BIAS_RELU><<<dim3(8, 64, 1), 256, 0, stream>>>(
      h1, w2b, h, b2, nullptr, 2048, 2048, 2048, 1024, 0, 0, 0, 0, 0);
  // ---- 3: [q/32 | k] = h @ wqkb^T + bqk   M=8192 N=2048 K=1024  [1024wg]
  gemm2s<EPI_BIAS_BF16><<<dim3(16, 64, 1), 256, 0, stream>>>(
      h, wqkb, qk, bqk, nullptr, 1024, 1024, 1024, 2048, 0, 0, 0, 0, 0);
  // ---- 4: v = h @ wv^T + bv   M=8192 N=1024 K=1024  [512wg]
  gemm2s<EPI_BIAS_BF16><<<dim3(8, 64, 1), 256, 0, stream>>>(
      h, wvb, vb, bv, nullptr, 1024, 1024, 1024, 1024, 0, 0, 0, 0, 0);
  // ---- v^T per batch (2048x1024 -> 1024x2048)
  transpose_bf16<<<dim3(16, 32, 4), 256, 0, stream>>>(
      vb, vT, 2048, 1024, 1024, 2048LL * 1024, 1024LL * 2048);
  // ---- 5: S = qhat @ k^T (scale pre-folded), batched z=4  [1024wg]
  gemm2s<EPI_PLAIN_BF16><<<dim3(16, 16, 4), 256, 0, stream>>>(
      qk, qk + 1024, S, nullptr, nullptr, 1024, 2048, 2048, 2048, 0,
      2048LL * 2048, 2048LL * 2048, 2048LL * 2048, 0);
  // ---- 6: P = softmax(S) in-place
  softmax_rows<<<8192, 256, 0, stream>>>(S);
  // ---- 7: ctx = P @ vT^T + v, batched   M=2048 N=1024 K=2048  [512wg]
  gemm2s<EPI_RESID><<<dim3(8, 16, 4), 256, 0, stream>>>(
      S, vT, ctx, nullptr, vb, 2048, 2048, 2048, 1024, 1024,
      2048LL * 2048, 1024LL * 2048, 2048LL * 1024, 2048LL * 1024);
  // ---- 8: out = ctx @ wo^T + bo (fp32)   M=8192 N=1024 K=1024  [512wg]
  gemm2s<EPI_BIAS_F32><<<dim3(8, 64, 1), 256, 0, stream>>>(
      ctx, wob, out, bo, nullptr, 1024, 1024, 1024, 1024, 0, 0, 0, 0, 0);
}